// Round 3
// baseline (527.748 us; speedup 1.0000x reference)
//
#include <hip/hip_runtime.h>
#include <math.h>

// Problem constants (B=1): S=4096, D=128, NHEADS=4, hd=32, N_COE=50, N_SCALES=4, THRE=5
//
// ws layout (floats):
//   eig   @ 0         (4096*128  = 524288)
//   qkv   @ 524288    (4096*384  = 1572864)
//   O     @ 2097152   (4096*128  = 524288)
//   xsum  @ 2621440   (128)
//   coef  @ 2621568   (104; pad to 256)
//   Opart @ 2621696   (8*4*4096*32 = 4194304)
//   ml    @ 6816000   (8*4*4096*2 = 262144)
// total ~28.3 MB

#define KSPLIT 8

// ---------------- K1: sine encoding + eig = eeig @ W + b ----------------
__global__ __launch_bounds__(256) void k_eig(const float* __restrict__ eve,
    const float* __restrict__ W, const float* __restrict__ bias,
    float* __restrict__ eig)
{
    __shared__ __align__(16) float se[16][132];   // [0..63]=sin, [64..127]=cos, [128]=e
    const int t = threadIdx.x;
    const int r0 = blockIdx.x * 16;
    {
        const int r = t >> 4, l = t & 15;
        const float e = eve[r0 + r];
        if (l == 0) se[r][128] = e;
        const float e100 = e * 100.0f;
        #pragma unroll
        for (int jj = 0; jj < 4; ++jj) {
            const int j = l * 4 + jj;             // 0..63
            const float div = expf(-0.07195578415606394f * (float)(2 * j));
            const float pe = e100 * div;
            se[r][j]      = sinf(pe);
            se[r][64 + j] = cosf(pe);
        }
    }
    __syncthreads();
    const int c = t & 127;
    const int rg = t >> 7;
    float acc[8];
    {
        const float w0 = W[c];                    // W row 0 pairs with raw e
        #pragma unroll
        for (int i = 0; i < 8; ++i) acc[i] = se[rg + 2 * i][128] * w0;
    }
    for (int k = 0; k < 128; k += 4) {            // se[.][k] pairs W[k+1]
        const float w0 = W[(k + 1) * 128 + c];
        const float w1 = W[(k + 2) * 128 + c];
        const float w2 = W[(k + 3) * 128 + c];
        const float w3 = W[(k + 4) * 128 + c];
        #pragma unroll
        for (int i = 0; i < 8; ++i) {
            const float4 x = *(const float4*)&se[rg + 2 * i][k];
            float a = acc[i];
            a = fmaf(x.x, w0, a);
            a = fmaf(x.y, w1, a);
            a = fmaf(x.z, w2, a);
            a = fmaf(x.w, w3, a);
            acc[i] = a;
        }
    }
    const float bb = bias[c];
    #pragma unroll
    for (int i = 0; i < 8; ++i) eig[(r0 + rg + 2 * i) * 128 + c] = acc[i] + bb;
}

// ---------------- K2: LN1 + qkv = ln(eig) @ in_W + in_b (3 panels fused over one x read) ----------------
__global__ __launch_bounds__(256) void k_qkv(const float* __restrict__ eig,
    const float* __restrict__ g, const float* __restrict__ b,
    const float* __restrict__ inW, const float* __restrict__ inb,
    float* __restrict__ qkv)
{
    __shared__ __align__(16) float xn[16][128];
    __shared__ float red1[16][16];
    __shared__ float red2[16][16];
    const int t = threadIdx.x;
    const int r0 = blockIdx.x * 16;
    const int r = t >> 4, l = t & 15;
    float v[8];
    {
        float s = 0.f, ss = 0.f;
        #pragma unroll
        for (int m = 0; m < 8; ++m) {
            const float x = eig[(r0 + r) * 128 + l + 16 * m];
            v[m] = x; s += x; ss += x * x;
        }
        red1[r][l] = s; red2[r][l] = ss;
    }
    __syncthreads();
    for (int o = 8; o > 0; o >>= 1) {
        if (l < o) { red1[r][l] += red1[r][l + o]; red2[r][l] += red2[r][l + o]; }
        __syncthreads();
    }
    {
        const float mean = red1[r][0] * (1.f / 128.f);
        const float var  = red2[r][0] * (1.f / 128.f) - mean * mean;
        const float inv  = 1.f / sqrtf(var + 1e-5f);
        #pragma unroll
        for (int m = 0; m < 8; ++m) {
            const int col = l + 16 * m;
            xn[r][col] = (v[m] - mean) * inv * g[col] + b[col];
        }
    }
    __syncthreads();
    const int cbase = t & 127;
    const int rg = t >> 7;
    float acc[3][8];
    #pragma unroll
    for (int p = 0; p < 3; ++p) {
        const float bb = inb[p * 128 + cbase];
        #pragma unroll
        for (int i = 0; i < 8; ++i) acc[p][i] = bb;
    }
    for (int k = 0; k < 128; k += 4) {
        float4 xv[8];
        #pragma unroll
        for (int i = 0; i < 8; ++i) xv[i] = *(const float4*)&xn[rg + 2 * i][k];
        #pragma unroll
        for (int p = 0; p < 3; ++p) {
            const int c = p * 128 + cbase;
            const float w0 = inW[(k + 0) * 384 + c];
            const float w1 = inW[(k + 1) * 384 + c];
            const float w2 = inW[(k + 2) * 384 + c];
            const float w3 = inW[(k + 3) * 384 + c];
            #pragma unroll
            for (int i = 0; i < 8; ++i) {
                float a = acc[p][i];
                a = fmaf(xv[i].x, w0, a);
                a = fmaf(xv[i].y, w1, a);
                a = fmaf(xv[i].z, w2, a);
                a = fmaf(xv[i].w, w3, a);
                acc[p][i] = a;
            }
        }
    }
    #pragma unroll
    for (int p = 0; p < 3; ++p)
        #pragma unroll
        for (int i = 0; i < 8; ++i)
            qkv[(r0 + rg + 2 * i) * 384 + p * 128 + cbase] = acc[p][i];
}

// ---------------- K3: flash attention partials; K/V workgroup-uniform -> s_load ----------------
// __launch_bounds__(256, 2): grid gives 2 blocks/CU = 2 waves/EU; budget 256 VGPR/wave so
// q[32]+acc[32]+p[16] stay register-resident (round-2 cap of 48 VGPRs caused spills/reloads).
__global__ __launch_bounds__(256, 2) void k_attn(const float* __restrict__ qkv,
    const int* __restrict__ sele, float* __restrict__ Opart, float* __restrict__ ml)
{
    const int t = threadIdx.x;
    const int lane = t & 63;
    const int w = t >> 6;                 // 4 waves = 4 query sub-tiles (queries differ; keys uniform)
    const int qt = blockIdx.x;            // 16 tiles of 256 queries
    const int h = blockIdx.y;             // 4 heads
    const int ks = blockIdx.z;            // 8 key splits
    const int sq = qt * 256 + w * 64 + lane;
    const int nk = sele[0];
    const float scl = 0.17677669529663687f;  // 1/sqrt(32)
    float q[32];
    {
        const float* __restrict__ qr = qkv + (size_t)sq * 384 + h * 32;
        #pragma unroll
        for (int d = 0; d < 32; ++d) q[d] = qr[d] * scl;
    }
    float m = -1e30f, lsum = 0.f;
    float acc[32];
    #pragma unroll
    for (int d = 0; d < 32; ++d) acc[d] = 0.f;
    const int k0 = ks * 512;
    for (int kc = k0; kc < k0 + 512; kc += 16) {
        float p[16];                       // scores, then probabilities (in place)
        #pragma unroll
        for (int c = 0; c < 16; ++c) {
            // address depends only on blockIdx + loop induction -> uniform -> s_load
            const float* __restrict__ kr = qkv + (size_t)(kc + c) * 384 + 128 + h * 32;
            float s = 0.f;
            #pragma unroll
            for (int d = 0; d < 32; ++d) s = fmaf(q[d], kr[d], s);
            p[c] = (kc + c < nk) ? s : -1e30f;
        }
        float cm = m;
        #pragma unroll
        for (int c = 0; c < 16; ++c) cm = fmaxf(cm, p[c]);
        const float al = __expf(m - cm);
        float ps = 0.f;
        #pragma unroll
        for (int c = 0; c < 16; ++c) {
            p[c] = (kc + c < nk) ? __expf(p[c] - cm) : 0.f;
            ps += p[c];
        }
        m = cm;
        lsum = lsum * al + ps;
        #pragma unroll
        for (int d = 0; d < 32; ++d) acc[d] *= al;
        #pragma unroll
        for (int c = 0; c < 16; ++c) {
            const float* __restrict__ vr = qkv + (size_t)(kc + c) * 384 + 256 + h * 32; // uniform
            const float pc = p[c];
            #pragma unroll
            for (int d = 0; d < 32; ++d) acc[d] = fmaf(pc, vr[d], acc[d]);
        }
    }
    const size_t pidx = ((size_t)(ks * 4 + h)) * 4096 + sq;
    float* __restrict__ op = Opart + pidx * 32;
    #pragma unroll
    for (int d = 0; d < 32; d += 4)
        *(float4*)&op[d] = make_float4(acc[d], acc[d + 1], acc[d + 2], acc[d + 3]);
    ml[pidx * 2]     = m;
    ml[pidx * 2 + 1] = lsum;
}

// ---------------- K3b: merge 8 key-split partials ----------------
__global__ __launch_bounds__(256) void k_merge(const float* __restrict__ Opart,
    const float* __restrict__ ml, float* __restrict__ O)
{
    const int gid = blockIdx.x * 256 + threadIdx.x;   // 4096*4*8 threads
    const int dg = gid & 7;
    const int h  = (gid >> 3) & 3;
    const int q  = gid >> 5;
    float mv[KSPLIT], lv[KSPLIT];
    float mm = -1e30f;
    #pragma unroll
    for (int s = 0; s < KSPLIT; ++s) {
        const size_t pidx = ((size_t)(s * 4 + h)) * 4096 + q;
        mv[s] = ml[pidx * 2];
        lv[s] = ml[pidx * 2 + 1];
        mm = fmaxf(mm, mv[s]);
    }
    float wt[KSPLIT], ll = 0.f;
    #pragma unroll
    for (int s = 0; s < KSPLIT; ++s) {
        wt[s] = __expf(mv[s] - mm);
        ll += lv[s] * wt[s];
    }
    const float inv = 1.f / ll;
    float o[4] = {0.f, 0.f, 0.f, 0.f};
    #pragma unroll
    for (int s = 0; s < KSPLIT; ++s) {
        const size_t base = (((size_t)(s * 4 + h)) * 4096 + q) * 32 + dg * 4;
        const float4 v = *(const float4*)&Opart[base];
        o[0] = fmaf(wt[s], v.x, o[0]);
        o[1] = fmaf(wt[s], v.y, o[1]);
        o[2] = fmaf(wt[s], v.z, o[2]);
        o[3] = fmaf(wt[s], v.w, o[3]);
    }
    float4 r = make_float4(o[0] * inv, o[1] * inv, o[2] * inv, o[3] * inv);
    *(float4*)&O[(size_t)q * 128 + h * 32 + dg * 4] = r;
}

// ---------------- K4: out-proj + residual + LN2 + FFN + residual + column-sum ----------------
__global__ __launch_bounds__(256) void k_ffn(const float* __restrict__ eig,
    const float* __restrict__ Oin,
    const float* __restrict__ outW, const float* __restrict__ outb,
    const float* __restrict__ lg, const float* __restrict__ lb,
    const float* __restrict__ W1, const float* __restrict__ b1,
    const float* __restrict__ W2, const float* __restrict__ b2,
    const int* __restrict__ sele, float* __restrict__ xsum)
{
    __shared__ __align__(16) float sA[16][128];   // O rows, later gelu(h)
    __shared__ __align__(16) float x2[16][128];   // residual stream
    __shared__ __align__(16) float xn[16][128];   // LN2 output
    __shared__ float red1[16][16];
    __shared__ float red2[16][16];
    __shared__ float colsum[2][128];
    const int t = threadIdx.x;
    const int r0 = blockIdx.x * 16;
    const int r = t >> 4, l = t & 15;
    #pragma unroll
    for (int m = 0; m < 8; ++m)
        sA[r][l + 16 * m] = Oin[(r0 + r) * 128 + l + 16 * m];
    __syncthreads();
    const int c = t & 127;
    const int rg = t >> 7;
    {   // out projection + residual
        float acc[8];
        const float bb = outb[c];
        #pragma unroll
        for (int i = 0; i < 8; ++i) acc[i] = bb;
        for (int k = 0; k < 128; k += 4) {
            const float w0 = outW[(k + 0) * 128 + c];
            const float w1 = outW[(k + 1) * 128 + c];
            const float w2 = outW[(k + 2) * 128 + c];
            const float w3 = outW[(k + 3) * 128 + c];
            #pragma unroll
            for (int i = 0; i < 8; ++i) {
                const float4 x = *(const float4*)&sA[rg + 2 * i][k];
                float a = acc[i];
                a = fmaf(x.x, w0, a);
                a = fmaf(x.y, w1, a);
                a = fmaf(x.z, w2, a);
                a = fmaf(x.w, w3, a);
                acc[i] = a;
            }
        }
        #pragma unroll
        for (int i = 0; i < 8; ++i)
            x2[rg + 2 * i][c] = eig[(r0 + rg + 2 * i) * 128 + c] + acc[i];
    }
    __syncthreads();
    {   // LN2
        float s = 0.f, ss = 0.f;
        float v[8];
        #pragma unroll
        for (int m = 0; m < 8; ++m) {
            const float x = x2[r][l + 16 * m];
            v[m] = x; s += x; ss += x * x;
        }
        red1[r][l] = s; red2[r][l] = ss;
        __syncthreads();
        for (int o = 8; o > 0; o >>= 1) {
            if (l < o) { red1[r][l] += red1[r][l + o]; red2[r][l] += red2[r][l + o]; }
            __syncthreads();
        }
        const float mean = red1[r][0] * (1.f / 128.f);
        const float var  = red2[r][0] * (1.f / 128.f) - mean * mean;
        const float inv  = 1.f / sqrtf(var + 1e-5f);
        #pragma unroll
        for (int m = 0; m < 8; ++m) {
            const int col = l + 16 * m;
            xn[r][col] = (v[m] - mean) * inv * lg[col] + lb[col];
        }
    }
    __syncthreads();
    {   // FFN1 + exact gelu -> sA
        float acc[8];
        const float bb = b1[c];
        #pragma unroll
        for (int i = 0; i < 8; ++i) acc[i] = bb;
        for (int k = 0; k < 128; k += 4) {
            const float w0 = W1[(k + 0) * 128 + c];
            const float w1 = W1[(k + 1) * 128 + c];
            const float w2 = W1[(k + 2) * 128 + c];
            const float w3 = W1[(k + 3) * 128 + c];
            #pragma unroll
            for (int i = 0; i < 8; ++i) {
                const float4 x = *(const float4*)&xn[rg + 2 * i][k];
                float a = acc[i];
                a = fmaf(x.x, w0, a);
                a = fmaf(x.y, w1, a);
                a = fmaf(x.z, w2, a);
                a = fmaf(x.w, w3, a);
                acc[i] = a;
            }
        }
        __syncthreads();
        #pragma unroll
        for (int i = 0; i < 8; ++i) {
            const float x = acc[i];
            sA[rg + 2 * i][c] = 0.5f * x * (1.f + erff(x * 0.70710678118654752f));
        }
    }
    __syncthreads();
    {   // FFN2 + residual + masked column sum
        float acc[8];
        const float bb = b2[c];
        #pragma unroll
        for (int i = 0; i < 8; ++i) acc[i] = bb;
        for (int k = 0; k < 128; k += 4) {
            const float w0 = W2[(k + 0) * 128 + c];
            const float w1 = W2[(k + 1) * 128 + c];
            const float w2 = W2[(k + 2) * 128 + c];
            const float w3 = W2[(k + 3) * 128 + c];
            #pragma unroll
            for (int i = 0; i < 8; ++i) {
                const float4 x = *(const float4*)&sA[rg + 2 * i][k];
                float a = acc[i];
                a = fmaf(x.x, w0, a);
                a = fmaf(x.y, w1, a);
                a = fmaf(x.z, w2, a);
                a = fmaf(x.w, w3, a);
                acc[i] = a;
            }
        }
        const int nsel = sele[0];
        float local = 0.f;
        #pragma unroll
        for (int i = 0; i < 8; ++i) {
            const float ef = x2[rg + 2 * i][c] + acc[i];
            if (r0 + rg + 2 * i < nsel) local += ef;
        }
        colsum[rg][c] = local;
    }
    __syncthreads();
    if (rg == 0) atomicAdd(&xsum[c], colsum[0][c] + colsum[1][c]);
}

// ---------------- K5: pooled coefficients ----------------
__global__ __launch_bounds__(128) void k_coef(const float* __restrict__ xsum,
    const float* __restrict__ dscW, const float* __restrict__ dscb,
    const float* __restrict__ dwvW, const float* __restrict__ dwvb,
    const float* __restrict__ dssW, const float* __restrict__ dssb,
    const int* __restrict__ len, const int* __restrict__ sele,
    float* __restrict__ coef)
{
    __shared__ float xs[128];
    __shared__ float csc[50], cwv[50];
    __shared__ float s2[2];
    const int t = threadIdx.x;
    xs[t] = xsum[t];
    __syncthreads();
    const float invl = 1.f / ((float)len[0] + 1e-8f);
    const float ns = (float)sele[0];
    if (t < 50) {
        float a = ns * dscb[t];
        for (int k = 0; k < 128; ++k) a = fmaf(xs[k], dscW[k * 50 + t], a);
        a *= invl;
        csc[t] = 1.f / (1.f + expf(-a));
    } else if (t >= 64 && t < 114) {
        const int j = t - 64;
        float a = ns * dwvb[j];
        for (int k = 0; k < 128; ++k) a = fmaf(xs[k], dwvW[k * 50 + j], a);
        a *= invl;
        cwv[j] = 1.f / (1.f + expf(-a));
    } else if (t >= 114 && t < 118) {
        const int j = t - 114;
        float a = ns * dssb[j];
        for (int k = 0; k < 128; ++k) a = fmaf(xs[k], dssW[k * 4 + j], a);
        a *= invl;
        coef[100 + j] = (1.f / (1.f + expf(-a))) * 5.0f;  // THRE
    }
    __syncthreads();
    if (t == 0) { float s = 0.f; for (int i2 = 0; i2 < 50; ++i2) s += csc[i2]; s2[0] = s; }
    if (t == 1) { float s = 0.f; for (int i2 = 0; i2 < 50; ++i2) s += cwv[i2]; s2[1] = s; }
    __syncthreads();
    if (t < 50) {
        coef[t]      = csc[t] / (s2[0] + 1e-8f);
        coef[50 + t] = cwv[t] / (s2[1] + 1e-8f);
    }
}

// ---------------- K6: Chebyshev bases + combine + normalize ----------------
__global__ __launch_bounds__(256) void k_out(const float* __restrict__ eve,
    const float* __restrict__ coef, float* __restrict__ out)
{
    __shared__ float csc[50], cwv[50], cs[4];
    const int t = threadIdx.x;
    if (t < 50) csc[t] = coef[t];
    else if (t < 100) cwv[t - 50] = coef[t];
    else if (t < 104) cs[t - 100] = coef[t];
    __syncthreads();
    const int s = blockIdx.x * 256 + t;
    const float e = eve[s];
    float vals[5];
    {   // scaling: [T1, T3, ..., T99](e-1); 0.5*(1-T)
        const float y = e - 1.f;
        float te = 1.f, to = y;
        float a = csc[0] * (0.5f * (1.f - to));
        const float y2 = 2.f * y;
        for (int i = 1; i < 50; ++i) {
            te = fmaf(y2, to, -te);
            to = fmaf(y2, te, -to);
            a = fmaf(csc[i], 0.5f * (1.f - to), a);
        }
        vals[0] = a;
    }
    #pragma unroll
    for (int j = 0; j < 4; ++j) {  // wavelet: [T0, T2, ..., T98](fsw-1)
        float f = e * cs[j];
        if (f > 2.f) f = 0.f;
        const float y = f - 1.f;
        float te = 1.f, to = y;
        float a = cwv[0] * (0.5f * (1.f - te));
        const float y2 = 2.f * y;
        for (int i = 1; i < 50; ++i) {
            te = fmaf(y2, to, -te);
            to = fmaf(y2, te, -to);
            a = fmaf(cwv[i], 0.5f * (1.f - te), a);
        }
        vals[1 + j] = a;
    }
    float n2 = 0.f;
    #pragma unroll
    for (int k = 0; k < 5; ++k) n2 += vals[k] * vals[k];
    const float invn = 1.f / (sqrtf(n2) + 1e-8f);
    #pragma unroll
    for (int k = 0; k < 5; ++k) out[s * 5 + k] = vals[k] * invn;
}

extern "C" void kernel_launch(void* const* d_in, const int* in_sizes, int n_in,
                              void* d_out, int out_size, void* d_ws, size_t ws_size,
                              hipStream_t stream) {
    const float* eve  = (const float*)d_in[0];
    const int*   len  = (const int*)d_in[1];
    const int*   sele = (const int*)d_in[2];
    const float* eigW = (const float*)d_in[3];
    const float* eigB = (const float*)d_in[4];
    const float* mlg  = (const float*)d_in[5];
    const float* mlb  = (const float*)d_in[6];
    const float* inW  = (const float*)d_in[7];
    const float* inb  = (const float*)d_in[8];
    const float* outW = (const float*)d_in[9];
    const float* outb = (const float*)d_in[10];
    const float* flg  = (const float*)d_in[11];
    const float* flb  = (const float*)d_in[12];
    const float* W1   = (const float*)d_in[13];
    const float* b1   = (const float*)d_in[14];
    const float* W2   = (const float*)d_in[15];
    const float* b2   = (const float*)d_in[16];
    const float* dscW = (const float*)d_in[17];
    const float* dscb = (const float*)d_in[18];
    const float* dwvW = (const float*)d_in[19];
    const float* dwvb = (const float*)d_in[20];
    const float* dssW = (const float*)d_in[21];
    const float* dssb = (const float*)d_in[22];

    float* ws    = (float*)d_ws;
    float* eig   = ws;
    float* qkv   = ws + 524288;
    float* O     = ws + 2097152;
    float* xsum  = ws + 2621440;
    float* coef  = ws + 2621568;
    float* Opart = ws + 2621696;
    float* ml    = ws + 6816000;
    float* out   = (float*)d_out;

    hipMemsetAsync(xsum, 0, 128 * sizeof(float), stream);
    k_eig  <<<256, 256, 0, stream>>>(eve, eigW, eigB, eig);
    k_qkv  <<<256, 256, 0, stream>>>(eig, mlg, mlb, inW, inb, qkv);
    k_attn <<<dim3(16, 4, KSPLIT), 256, 0, stream>>>(qkv, sele, Opart, ml);
    k_merge<<<512, 256, 0, stream>>>(Opart, ml, O);
    k_ffn  <<<256, 256, 0, stream>>>(eig, O, outW, outb, flg, flb, W1, b1, W2, b2, sele, xsum);
    k_coef <<<1, 128, 0, stream>>>(xsum, dscW, dscb, dwvW, dwvb, dssW, dssb, len, sele, coef);
    k_out  <<<16, 256, 0, stream>>>(eve, coef, out);
}

// Round 4
// 394.195 us; speedup vs baseline: 1.3388x; 1.3388x over previous
//
#include <hip/hip_runtime.h>
#include <math.h>

// Problem constants (B=1): S=4096, D=128, NHEADS=4, hd=32, N_COE=50, N_SCALES=4, THRE=5
//
// ws layout (floats):
//   eig  @ 0        (4096*128  = 524288)
//   qkv  @ 524288   (4096*384  = 1572864)
//   Oe   @ 2097152  (4*4096*128 = 2097152)   exp-weighted V partials, 4 key-quarter slots
//   E    @ 4194304  (4*4*4096   = 65536)     exp sums, [kq][h][q]
//   xsum @ 4259840  (128)
//   coef @ 4259968  (104; pad)
// total ~17 MB

// ---------------- K1: sine encoding + eig = eeig @ W + b ----------------
__global__ __launch_bounds__(256) void k_eig(const float* __restrict__ eve,
    const float* __restrict__ W, const float* __restrict__ bias,
    float* __restrict__ eig)
{
    __shared__ __align__(16) float se[16][132];   // [0..63]=sin, [64..127]=cos, [128]=e
    const int t = threadIdx.x;
    const int r0 = blockIdx.x * 16;
    {
        const int r = t >> 4, l = t & 15;
        const float e = eve[r0 + r];
        if (l == 0) se[r][128] = e;
        const float e100 = e * 100.0f;
        #pragma unroll
        for (int jj = 0; jj < 4; ++jj) {
            const int j = l * 4 + jj;             // 0..63
            const float div = expf(-0.07195578415606394f * (float)(2 * j));
            const float pe = e100 * div;
            se[r][j]      = sinf(pe);
            se[r][64 + j] = cosf(pe);
        }
    }
    __syncthreads();
    const int c = t & 127;
    const int rg = t >> 7;
    float acc[8];
    {
        const float w0 = W[c];                    // W row 0 pairs with raw e
        #pragma unroll
        for (int i = 0; i < 8; ++i) acc[i] = se[rg + 2 * i][128] * w0;
    }
    for (int k = 0; k < 128; k += 4) {            // se[.][k] pairs W[k+1]
        const float w0 = W[(k + 1) * 128 + c];
        const float w1 = W[(k + 2) * 128 + c];
        const float w2 = W[(k + 3) * 128 + c];
        const float w3 = W[(k + 4) * 128 + c];
        #pragma unroll
        for (int i = 0; i < 8; ++i) {
            const float4 x = *(const float4*)&se[rg + 2 * i][k];
            float a = acc[i];
            a = fmaf(x.x, w0, a);
            a = fmaf(x.y, w1, a);
            a = fmaf(x.z, w2, a);
            a = fmaf(x.w, w3, a);
            acc[i] = a;
        }
    }
    const float bb = bias[c];
    #pragma unroll
    for (int i = 0; i < 8; ++i) eig[(r0 + rg + 2 * i) * 128 + c] = acc[i] + bb;
}

// ---------------- K2: LN1 + qkv = ln(eig) @ in_W + in_b ----------------
__global__ __launch_bounds__(256) void k_qkv(const float* __restrict__ eig,
    const float* __restrict__ g, const float* __restrict__ b,
    const float* __restrict__ inW, const float* __restrict__ inb,
    float* __restrict__ qkv)
{
    __shared__ __align__(16) float xn[16][128];
    __shared__ float red1[16][16];
    __shared__ float red2[16][16];
    const int t = threadIdx.x;
    const int r0 = blockIdx.x * 16;
    const int r = t >> 4, l = t & 15;
    float v[8];
    {
        float s = 0.f, ss = 0.f;
        #pragma unroll
        for (int m = 0; m < 8; ++m) {
            const float x = eig[(r0 + r) * 128 + l + 16 * m];
            v[m] = x; s += x; ss += x * x;
        }
        red1[r][l] = s; red2[r][l] = ss;
    }
    __syncthreads();
    for (int o = 8; o > 0; o >>= 1) {
        if (l < o) { red1[r][l] += red1[r][l + o]; red2[r][l] += red2[r][l + o]; }
        __syncthreads();
    }
    {
        const float mean = red1[r][0] * (1.f / 128.f);
        const float var  = red2[r][0] * (1.f / 128.f) - mean * mean;
        const float inv  = 1.f / sqrtf(var + 1e-5f);
        #pragma unroll
        for (int m = 0; m < 8; ++m) {
            const int col = l + 16 * m;
            xn[r][col] = (v[m] - mean) * inv * g[col] + b[col];
        }
    }
    __syncthreads();
    const int cbase = t & 127;
    const int rg = t >> 7;
    float acc[3][8];
    #pragma unroll
    for (int p = 0; p < 3; ++p) {
        const float bb = inb[p * 128 + cbase];
        #pragma unroll
        for (int i = 0; i < 8; ++i) acc[p][i] = bb;
    }
    for (int k = 0; k < 128; k += 4) {
        float4 xv[8];
        #pragma unroll
        for (int i = 0; i < 8; ++i) xv[i] = *(const float4*)&xn[rg + 2 * i][k];
        #pragma unroll
        for (int p = 0; p < 3; ++p) {
            const int c = p * 128 + cbase;
            const float w0 = inW[(k + 0) * 384 + c];
            const float w1 = inW[(k + 1) * 384 + c];
            const float w2 = inW[(k + 2) * 384 + c];
            const float w3 = inW[(k + 3) * 384 + c];
            #pragma unroll
            for (int i = 0; i < 8; ++i) {
                float a = acc[p][i];
                a = fmaf(xv[i].x, w0, a);
                a = fmaf(xv[i].y, w1, a);
                a = fmaf(xv[i].z, w2, a);
                a = fmaf(xv[i].w, w3, a);
                acc[p][i] = a;
            }
        }
    }
    #pragma unroll
    for (int p = 0; p < 3; ++p)
        #pragma unroll
        for (int i = 0; i < 8; ++i)
            qkv[(r0 + rg + 2 * i) * 384 + p * 128 + cbase] = acc[p][i];
}

// ---------------- K3: attention, no-max softmax partials ----------------
// Wave = (64 queries in lanes) x (256-key range). Key range from readfirstlane(waveid)
// so K/V addresses stay provably wave-uniform -> s_load. Scores bounded (|s|<~65) so
// exp without max-subtraction is safe in fp32 and partials are linear:
// E = sum exp(s), Oe = sum exp(s)*V. 4 waves merge via LDS atomics; block writes slot kq.
__global__ __launch_bounds__(256, 4) void k_attn(const float* __restrict__ qkv,
    const int* __restrict__ sele, float* __restrict__ Oe, float* __restrict__ E)
{
    __shared__ float sOe[64][33];
    __shared__ float sE[64];
    const int t = threadIdx.x;
    const int lane = t & 63;
    const int wv = __builtin_amdgcn_readfirstlane(t >> 6);  // 0..3, wave-uniform in SGPR
    const int qt = blockIdx.x;            // 64 q-tiles of 64
    const int h  = blockIdx.y;            // 4 heads
    const int kq = blockIdx.z;            // 4 key quarters
    const int sq = qt * 64 + lane;
    const int nk = sele[0];
    for (int i = t; i < 64 * 33; i += 256) ((float*)sOe)[i] = 0.f;
    if (t < 64) sE[t] = 0.f;
    __syncthreads();

    const float scl = 0.17677669529663687f;  // 1/sqrt(32)
    float q[32];
    {
        const float* __restrict__ qr = qkv + (size_t)sq * 384 + h * 32;
        #pragma unroll
        for (int d = 0; d < 32; ++d) q[d] = qr[d] * scl;
    }
    float lsum = 0.f;
    float acc[32];
    #pragma unroll
    for (int d = 0; d < 32; ++d) acc[d] = 0.f;

    const int k0 = kq * 1024 + wv * 256;
    for (int kc = k0; kc < k0 + 256; kc += 4) {
        float p[4];
        #pragma unroll
        for (int c = 0; c < 4; ++c) {
            const float* __restrict__ kr = qkv + (size_t)(kc + c) * 384 + 128 + h * 32;
            float s = 0.f;
            #pragma unroll
            for (int d = 0; d < 32; ++d) s = fmaf(q[d], kr[d], s);
            p[c] = (kc + c < nk) ? __expf(s) : 0.f;
        }
        lsum += (p[0] + p[1]) + (p[2] + p[3]);
        #pragma unroll
        for (int c = 0; c < 4; ++c) {
            const float* __restrict__ vr = qkv + (size_t)(kc + c) * 384 + 256 + h * 32;
            const float pc = p[c];
            #pragma unroll
            for (int d = 0; d < 32; ++d) acc[d] = fmaf(pc, vr[d], acc[d]);
        }
    }
    atomicAdd(&sE[lane], lsum);
    #pragma unroll
    for (int d = 0; d < 32; ++d) atomicAdd(&sOe[lane][d], acc[d]);
    __syncthreads();
    float* __restrict__ oeg = Oe + ((size_t)kq * 4096 + qt * 64) * 128 + h * 32;
    for (int i = t; i < 2048; i += 256) {
        const int q2 = i >> 5, d = i & 31;
        oeg[(size_t)q2 * 128 + d] = sOe[q2][d];
    }
    if (t < 64) E[((size_t)kq * 4 + h) * 4096 + qt * 64 + t] = sE[t];
}

// ---------------- K4: fold Oe/E + out-proj + residual + LN2 + FFN + residual + column-sum ----------------
__global__ __launch_bounds__(256) void k_ffn(const float* __restrict__ eig,
    const float* __restrict__ Oe, const float* __restrict__ E,
    const float* __restrict__ outW, const float* __restrict__ outb,
    const float* __restrict__ lg, const float* __restrict__ lb,
    const float* __restrict__ W1, const float* __restrict__ b1,
    const float* __restrict__ W2, const float* __restrict__ b2,
    const int* __restrict__ sele, float* __restrict__ xsum)
{
    __shared__ __align__(16) float sA[16][128];   // attention O rows, later gelu(h)
    __shared__ __align__(16) float x2[16][128];   // residual stream
    __shared__ __align__(16) float xn[16][128];   // LN2 output
    __shared__ float red1[16][16];
    __shared__ float red2[16][16];
    __shared__ float colsum[2][128];
    const int t = threadIdx.x;
    const int r0 = blockIdx.x * 16;
    const int r = t >> 4, l = t & 15;
    {   // fold 4 key-quarter slots and divide by E -> O row
        const int row = r0 + r;
        float rcpE[4];
        #pragma unroll
        for (int hh = 0; hh < 4; ++hh) {
            float es = 0.f;
            #pragma unroll
            for (int kq = 0; kq < 4; ++kq)
                es += E[((size_t)kq * 4 + hh) * 4096 + row];
            rcpE[hh] = 1.f / es;
        }
        #pragma unroll
        for (int m = 0; m < 8; ++m) {
            const int col = l + 16 * m;
            float v = 0.f;
            #pragma unroll
            for (int kq = 0; kq < 4; ++kq)
                v += Oe[((size_t)kq * 4096 + row) * 128 + col];
            sA[r][col] = v * rcpE[col >> 5];
        }
    }
    __syncthreads();
    const int c = t & 127;
    const int rg = t >> 7;
    {   // out projection + residual
        float acc[8];
        const float bb = outb[c];
        #pragma unroll
        for (int i = 0; i < 8; ++i) acc[i] = bb;
        for (int k = 0; k < 128; k += 4) {
            const float w0 = outW[(k + 0) * 128 + c];
            const float w1 = outW[(k + 1) * 128 + c];
            const float w2 = outW[(k + 2) * 128 + c];
            const float w3 = outW[(k + 3) * 128 + c];
            #pragma unroll
            for (int i = 0; i < 8; ++i) {
                const float4 x = *(const float4*)&sA[rg + 2 * i][k];
                float a = acc[i];
                a = fmaf(x.x, w0, a);
                a = fmaf(x.y, w1, a);
                a = fmaf(x.z, w2, a);
                a = fmaf(x.w, w3, a);
                acc[i] = a;
            }
        }
        #pragma unroll
        for (int i = 0; i < 8; ++i)
            x2[rg + 2 * i][c] = eig[(r0 + rg + 2 * i) * 128 + c] + acc[i];
    }
    __syncthreads();
    {   // LN2
        float s = 0.f, ss = 0.f;
        float v[8];
        #pragma unroll
        for (int m = 0; m < 8; ++m) {
            const float x = x2[r][l + 16 * m];
            v[m] = x; s += x; ss += x * x;
        }
        red1[r][l] = s; red2[r][l] = ss;
        __syncthreads();
        for (int o = 8; o > 0; o >>= 1) {
            if (l < o) { red1[r][l] += red1[r][l + o]; red2[r][l] += red2[r][l + o]; }
            __syncthreads();
        }
        const float mean = red1[r][0] * (1.f / 128.f);
        const float var  = red2[r][0] * (1.f / 128.f) - mean * mean;
        const float inv  = 1.f / sqrtf(var + 1e-5f);
        #pragma unroll
        for (int m = 0; m < 8; ++m) {
            const int col = l + 16 * m;
            xn[r][col] = (v[m] - mean) * inv * lg[col] + lb[col];
        }
    }
    __syncthreads();
    {   // FFN1 + exact gelu -> sA
        float acc[8];
        const float bb = b1[c];
        #pragma unroll
        for (int i = 0; i < 8; ++i) acc[i] = bb;
        for (int k = 0; k < 128; k += 4) {
            const float w0 = W1[(k + 0) * 128 + c];
            const float w1 = W1[(k + 1) * 128 + c];
            const float w2 = W1[(k + 2) * 128 + c];
            const float w3 = W1[(k + 3) * 128 + c];
            #pragma unroll
            for (int i = 0; i < 8; ++i) {
                const float4 x = *(const float4*)&xn[rg + 2 * i][k];
                float a = acc[i];
                a = fmaf(x.x, w0, a);
                a = fmaf(x.y, w1, a);
                a = fmaf(x.z, w2, a);
                a = fmaf(x.w, w3, a);
                acc[i] = a;
            }
        }
        __syncthreads();
        #pragma unroll
        for (int i = 0; i < 8; ++i) {
            const float x = acc[i];
            sA[rg + 2 * i][c] = 0.5f * x * (1.f + erff(x * 0.70710678118654752f));
        }
    }
    __syncthreads();
    {   // FFN2 + residual + masked column sum
        float acc[8];
        const float bb = b2[c];
        #pragma unroll
        for (int i = 0; i < 8; ++i) acc[i] = bb;
        for (int k = 0; k < 128; k += 4) {
            const float w0 = W2[(k + 0) * 128 + c];
            const float w1 = W2[(k + 1) * 128 + c];
            const float w2 = W2[(k + 2) * 128 + c];
            const float w3 = W2[(k + 3) * 128 + c];
            #pragma unroll
            for (int i = 0; i < 8; ++i) {
                const float4 x = *(const float4*)&sA[rg + 2 * i][k];
                float a = acc[i];
                a = fmaf(x.x, w0, a);
                a = fmaf(x.y, w1, a);
                a = fmaf(x.z, w2, a);
                a = fmaf(x.w, w3, a);
                acc[i] = a;
            }
        }
        const int nsel = sele[0];
        float local = 0.f;
        #pragma unroll
        for (int i = 0; i < 8; ++i) {
            const float ef = x2[rg + 2 * i][c] + acc[i];
            if (r0 + rg + 2 * i < nsel) local += ef;
        }
        colsum[rg][c] = local;
    }
    __syncthreads();
    if (rg == 0) atomicAdd(&xsum[c], colsum[0][c] + colsum[1][c]);
}

// ---------------- K5: pooled coefficients ----------------
__global__ __launch_bounds__(128) void k_coef(const float* __restrict__ xsum,
    const float* __restrict__ dscW, const float* __restrict__ dscb,
    const float* __restrict__ dwvW, const float* __restrict__ dwvb,
    const float* __restrict__ dssW, const float* __restrict__ dssb,
    const int* __restrict__ len, const int* __restrict__ sele,
    float* __restrict__ coef)
{
    __shared__ float xs[128];
    __shared__ float csc[50], cwv[50];
    __shared__ float s2[2];
    const int t = threadIdx.x;
    xs[t] = xsum[t];
    __syncthreads();
    const float invl = 1.f / ((float)len[0] + 1e-8f);
    const float ns = (float)sele[0];
    if (t < 50) {
        float a = ns * dscb[t];
        for (int k = 0; k < 128; ++k) a = fmaf(xs[k], dscW[k * 50 + t], a);
        a *= invl;
        csc[t] = 1.f / (1.f + expf(-a));
    } else if (t >= 64 && t < 114) {
        const int j = t - 64;
        float a = ns * dwvb[j];
        for (int k = 0; k < 128; ++k) a = fmaf(xs[k], dwvW[k * 50 + j], a);
        a *= invl;
        cwv[j] = 1.f / (1.f + expf(-a));
    } else if (t >= 114 && t < 118) {
        const int j = t - 114;
        float a = ns * dssb[j];
        for (int k = 0; k < 128; ++k) a = fmaf(xs[k], dssW[k * 4 + j], a);
        a *= invl;
        coef[100 + j] = (1.f / (1.f + expf(-a))) * 5.0f;  // THRE
    }
    __syncthreads();
    if (t == 0) { float s = 0.f; for (int i2 = 0; i2 < 50; ++i2) s += csc[i2]; s2[0] = s; }
    if (t == 1) { float s = 0.f; for (int i2 = 0; i2 < 50; ++i2) s += cwv[i2]; s2[1] = s; }
    __syncthreads();
    if (t < 50) {
        coef[t]      = csc[t] / (s2[0] + 1e-8f);
        coef[50 + t] = cwv[t] / (s2[1] + 1e-8f);
    }
}

// ---------------- K6: Chebyshev bases + combine + normalize ----------------
__global__ __launch_bounds__(256) void k_out(const float* __restrict__ eve,
    const float* __restrict__ coef, float* __restrict__ out)
{
    __shared__ float csc[50], cwv[50], cs[4];
    const int t = threadIdx.x;
    if (t < 50) csc[t] = coef[t];
    else if (t < 100) cwv[t - 50] = coef[t];
    else if (t < 104) cs[t - 100] = coef[t];
    __syncthreads();
    const int s = blockIdx.x * 256 + t;
    const float e = eve[s];
    float vals[5];
    {   // scaling: [T1, T3, ..., T99](e-1); 0.5*(1-T)
        const float y = e - 1.f;
        float te = 1.f, to = y;
        float a = csc[0] * (0.5f * (1.f - to));
        const float y2 = 2.f * y;
        for (int i = 1; i < 50; ++i) {
            te = fmaf(y2, to, -te);
            to = fmaf(y2, te, -to);
            a = fmaf(csc[i], 0.5f * (1.f - to), a);
        }
        vals[0] = a;
    }
    #pragma unroll
    for (int j = 0; j < 4; ++j) {  // wavelet: [T0, T2, ..., T98](fsw-1)
        float f = e * cs[j];
        if (f > 2.f) f = 0.f;
        const float y = f - 1.f;
        float te = 1.f, to = y;
        float a = cwv[0] * (0.5f * (1.f - te));
        const float y2 = 2.f * y;
        for (int i = 1; i < 50; ++i) {
            te = fmaf(y2, to, -te);
            to = fmaf(y2, te, -to);
            a = fmaf(cwv[i], 0.5f * (1.f - te), a);
        }
        vals[1 + j] = a;
    }
    float n2 = 0.f;
    #pragma unroll
    for (int k = 0; k < 5; ++k) n2 += vals[k] * vals[k];
    const float invn = 1.f / (sqrtf(n2) + 1e-8f);
    #pragma unroll
    for (int k = 0; k < 5; ++k) out[s * 5 + k] = vals[k] * invn;
}

extern "C" void kernel_launch(void* const* d_in, const int* in_sizes, int n_in,
                              void* d_out, int out_size, void* d_ws, size_t ws_size,
                              hipStream_t stream) {
    const float* eve  = (const float*)d_in[0];
    const int*   len  = (const int*)d_in[1];
    const int*   sele = (const int*)d_in[2];
    const float* eigW = (const float*)d_in[3];
    const float* eigB = (const float*)d_in[4];
    const float* mlg  = (const float*)d_in[5];
    const float* mlb  = (const float*)d_in[6];
    const float* inW  = (const float*)d_in[7];
    const float* inb  = (const float*)d_in[8];
    const float* outW = (const float*)d_in[9];
    const float* outb = (const float*)d_in[10];
    const float* flg  = (const float*)d_in[11];
    const float* flb  = (const float*)d_in[12];
    const float* W1   = (const float*)d_in[13];
    const float* b1   = (const float*)d_in[14];
    const float* W2   = (const float*)d_in[15];
    const float* b2   = (const float*)d_in[16];
    const float* dscW = (const float*)d_in[17];
    const float* dscb = (const float*)d_in[18];
    const float* dwvW = (const float*)d_in[19];
    const float* dwvb = (const float*)d_in[20];
    const float* dssW = (const float*)d_in[21];
    const float* dssb = (const float*)d_in[22];

    float* ws   = (float*)d_ws;
    float* eig  = ws;
    float* qkv  = ws + 524288;
    float* Oe   = ws + 2097152;
    float* E    = ws + 4194304;
    float* xsum = ws + 4259840;
    float* coef = ws + 4259968;
    float* out  = (float*)d_out;

    hipMemsetAsync(xsum, 0, 128 * sizeof(float), stream);
    k_eig <<<256, 256, 0, stream>>>(eve, eigW, eigB, eig);
    k_qkv <<<256, 256, 0, stream>>>(eig, mlg, mlb, inW, inb, qkv);
    k_attn<<<dim3(64, 4, 4), 256, 0, stream>>>(qkv, sele, Oe, E);
    k_ffn <<<256, 256, 0, stream>>>(eig, Oe, E, outW, outb, flg, flb, W1, b1, W2, b2, sele, xsum);
    k_coef<<<1, 128, 0, stream>>>(xsum, dscW, dscb, dwvW, dwvb, dssW, dssb, len, sele, coef);
    k_out <<<16, 256, 0, stream>>>(eve, coef, out);
}